// Round 8
// baseline (392.051 us; speedup 1.0000x reference)
//
#include <hip/hip_runtime.h>
#include <hip/hip_bf16.h>

#define NQ 20
#define NLAY 51            // N_LAYER+1
#define FEAT 128
#define BATCH 128
#define NN (BATCH * NQ * NLAY)   // 130560
#define NE 524288
#define NPAIR (BATCH * NQ * NQ)  // 51200
#define NB (NN / 256)            // 510
#define VOCAB 1021

typedef _Float16 half8 __attribute__((ext_vector_type(8)));
typedef float floatx4 __attribute__((ext_vector_type(4)));
typedef unsigned int uint;

__device__ __forceinline__ float lrelu(float v) { return v >= 0.f ? v : 0.01f * v; }

// pack fp32 -> {fp16 hi (low16), fp16 lo (high16)}
__device__ __forceinline__ uint packhl(float v) {
    _Float16 h = (_Float16)v;
    _Float16 l = (_Float16)(v - (float)h);
    union { _Float16 f; unsigned short u; } hb, lb;
    hb.f = h; lb.f = l;
    return (uint)hb.u | ((uint)lb.u << 16);
}

// unpack 8 packed elems (2x uint4) into hi/lo half8 fragments via v_perm
__device__ __forceinline__ void unpack8(uint4 a, uint4 b, half8& hi, half8& lo) {
    union { uint u[4]; half8 h; } H, L;
    H.u[0] = __builtin_amdgcn_perm(a.y, a.x, 0x05040100u);
    H.u[1] = __builtin_amdgcn_perm(a.w, a.z, 0x05040100u);
    H.u[2] = __builtin_amdgcn_perm(b.y, b.x, 0x05040100u);
    H.u[3] = __builtin_amdgcn_perm(b.w, b.z, 0x05040100u);
    L.u[0] = __builtin_amdgcn_perm(a.y, a.x, 0x07060302u);
    L.u[1] = __builtin_amdgcn_perm(a.w, a.z, 0x07060302u);
    L.u[2] = __builtin_amdgcn_perm(b.y, b.x, 0x07060302u);
    L.u[3] = __builtin_amdgcn_perm(b.w, b.z, 0x07060302u);
    hi = H.h;
    lo = L.h;
}

// ---------------- CSR build ----------------
__global__ void k_count(const int* __restrict__ dst, int* __restrict__ cnt) {
    int e = blockIdx.x * 256 + threadIdx.x;
    atomicAdd(&cnt[dst[e]], 1);
}

// offsets via block-scan + global cursor; also dinv, meta, S0 seed, idmap.
__global__ void k_offsets(const int* __restrict__ cnt, const int* __restrict__ x,
                          int* __restrict__ offs, float* __restrict__ dinv,
                          int4* __restrict__ meta, int* __restrict__ cursor,
                          int* __restrict__ flag1, int* __restrict__ idmap) {
    __shared__ int sm[256];
    __shared__ int sbase;
    int t = threadIdx.x, g = blockIdx.x * 256 + t;
    int v = cnt[g];
    sm[t] = v;
    __syncthreads();
    for (int s = 1; s < 256; s <<= 1) {
        int add = (t >= s) ? sm[t - s] : 0;
        __syncthreads();
        sm[t] += add;
        __syncthreads();
    }
    if (t == 255) sbase = atomicAdd(cursor, sm[255]);
    __syncthreads();
    int off = sbase + sm[t] - v;
    float di = rsqrtf((float)(v + 1));  // +1 self loop
    offs[g] = off;
    dinv[g] = di;
    meta[g] = make_int4(off, v, __float_as_int(di), x[g]);
    if (g % (NQ * NLAY) < NQ) flag1[g] = 1;      // S0 seed
    if (g < 1024) idmap[g] = min(g, VOCAB - 1);
}

// fill packed edges {src, norm_bits} and token edges {x[src], norm_bits};
// norm = dinv[src]*dinv[dst]. Also mark flag1[src] for S0 dsts.
__global__ void k_fill(const int* __restrict__ src, const int* __restrict__ dst,
                       const int* __restrict__ offs, int* __restrict__ fill,
                       const float* __restrict__ dinv, const int* __restrict__ x,
                       int2* __restrict__ csre, int2* __restrict__ csre0,
                       int* __restrict__ flag1) {
    int e = blockIdx.x * 256 + threadIdx.x;
    int d = dst[e];
    int s = src[e];
    int pos = offs[d] + atomicAdd(&fill[d], 1);
    int wb = __float_as_int(dinv[s] * dinv[d]);
    csre[pos] = make_int2(s, wb);
    csre0[pos] = make_int2(x[s], wb);
    if (d % (NQ * NLAY) < NQ) flag1[s] = 1;      // src feeds an S0 node
}

// cone pass: emit packed 64B agg-records from flagI (cursor-packed dense prefix)
// and, if flagO, mark flagO = flagI-members ∪ their in-neighbors.
// Record layout (4 x int4): [0] = {node+1, deg, dinv^2, csr_off}
//                           [1..3] = 6 inline edges {src, norm_bits} (zero-padded)
// Trailing blocks (>= NB, when rec0q != nullptr) build the dense-S0 rec0 table.
__global__ void k_s1pass(const int* __restrict__ flagI, const int4* __restrict__ meta,
                         const int2* __restrict__ csre, int* __restrict__ cur,
                         int4* __restrict__ recO, int* __restrict__ flagO,
                         int4* __restrict__ rec0q) {
    if (rec0q && blockIdx.x >= NB) {
        int q = (blockIdx.x - NB) * 256 + threadIdx.x;
        if (q < BATCH * NQ) {
            int b = q / NQ, i = q - b * NQ;
            int node = b * (NQ * NLAY) + i;
            int4 m = meta[node];
            float di = __int_as_float(m.z);
            int dc = min(m.y, 6);
            int2 eb[6];
#pragma unroll
            for (int j = 0; j < 6; j++) eb[j] = (j < dc) ? csre[m.x + j] : make_int2(0, 0);
            int4* r = rec0q + (size_t)q * 4;
            r[0] = make_int4(node + 1, m.y, __float_as_int(di * di), m.x);
            r[1] = make_int4(eb[0].x, eb[0].y, eb[1].x, eb[1].y);
            r[2] = make_int4(eb[2].x, eb[2].y, eb[3].x, eb[3].y);
            r[3] = make_int4(eb[4].x, eb[4].y, eb[5].x, eb[5].y);
        }
        return;
    }
    __shared__ int sm[256];
    __shared__ int sbase;
    int t = threadIdx.x, g = blockIdx.x * 256 + t;
    int v = flagI[g];
    sm[t] = v;
    __syncthreads();
    for (int s = 1; s < 256; s <<= 1) {
        int add = (t >= s) ? sm[t - s] : 0;
        __syncthreads();
        sm[t] += add;
        __syncthreads();
    }
    if (t == 255) sbase = atomicAdd(cur, sm[255]);
    __syncthreads();
    if (v) {
        int slot = sbase + sm[t] - 1;
        int4 m = meta[g];
        float di = __int_as_float(m.z);
        int dc = min(m.y, 6);
        int2 eb[6];
#pragma unroll
        for (int j = 0; j < 6; j++) eb[j] = (j < dc) ? csre[m.x + j] : make_int2(0, 0);
        int4* r = recO + (size_t)slot * 4;
        r[0] = make_int4(g + 1, m.y, __float_as_int(di * di), m.x);
        r[1] = make_int4(eb[0].x, eb[0].y, eb[1].x, eb[1].y);
        r[2] = make_int4(eb[2].x, eb[2].y, eb[3].x, eb[3].y);
        r[3] = make_int4(eb[4].x, eb[4].y, eb[5].x, eb[5].y);
        if (flagO) {
            flagO[g] = 1;
            for (int e = 0; e < m.y; e++) flagO[csre[m.x + e].x] = 1;   // benign races
        }
    }
}

// ---------------- weight transpose + fp16 hi/lo split, PACKED MFMA-fragment layout -------
#define OFF_GCN 0                 // 5 x K=128 N=128
#define OFF_P0  81920             // combined mw0: K=128 N=512
#define OFF_M1  147456            // mw1: K=256 N=128
#define OFF_M2  180224            // mw2: K=128 N=128
#define OFF_M3  196608            // mw3: K=128 N=64
#define OFF_M4  204800            // mw4: K=64  N=64
#define TS_TOTAL 208896

__global__ void k_tsplit_all(const float* __restrict__ gw, const float* __restrict__ mw0,
                             const float* __restrict__ mw1, const float* __restrict__ mw2,
                             const float* __restrict__ mw3, const float* __restrict__ mw4,
                             _Float16* __restrict__ hi, _Float16* __restrict__ lo) {
    int idx = blockIdx.x * 256 + threadIdx.x;
    const float* src;
    int K, N, rel;
    bool p0 = false;
    if (idx < OFF_P0) {
        int L = (idx - OFF_GCN) >> 14; rel = (idx - OFF_GCN) & 16383;
        src = gw + L * 16384; K = 128; N = 128;
    } else if (idx < OFF_M1) {
        rel = idx - OFF_P0; src = mw0; K = 128; N = 512; p0 = true;
    } else if (idx < OFF_M2) {
        rel = idx - OFF_M1;  src = mw1; K = 256; N = 128;
    } else if (idx < OFF_M3) {
        rel = idx - OFF_M2;  src = mw2; K = 128; N = 128;
    } else if (idx < OFF_M4) {
        rel = idx - OFF_M3;  src = mw3; K = 128; N = 64;
    } else {
        rel = idx - OFF_M4;  src = mw4; K = 64;  N = 64;
    }
    int kblks = K >> 5;
    int j = rel & 7;
    int lane = (rel >> 3) & 63;
    int t2 = rel >> 9;
    int kblk = t2 % kblks;
    int ntile = t2 / kblks;
    int col = ntile * 16 + (lane & 15);
    int k = kblk * 32 + ((lane >> 4) << 3) + j;
    float f;
    if (p0) {
        f = (col < 256) ? src[k * 256 + col] : src[(k + 128) * 256 + (col - 256)];
    } else {
        f = src[k * N + col];
    }
    _Float16 h = (_Float16)f;
    hi[idx] = h;
    lo[idx] = (_Float16)(f - (float)h);
}

// ---------------- split-fp16 MFMA GEMM (layer-0 token table only) ----------------
template <int NT_N, bool LEAKY, bool BIAS, bool P0SPLIT, bool FUSEA, bool GATHA, bool LISTM>
__launch_bounds__(256, 2)
__global__ void hgemm(const float* __restrict__ A,
                      const float* __restrict__ FA, const float* __restrict__ FB,
                      const _Float16* __restrict__ Bh, const _Float16* __restrict__ Bl,
                      const float* __restrict__ bias,
                      float* __restrict__ C, float* __restrict__ C2,
                      int N, int K, const int* __restrict__ gmap,
                      const int* __restrict__ listm) {
    if (LISTM) {
        if ((unsigned)listm[blockIdx.x * 128] >= (unsigned)NN) return;  // all-sentinel block
    }
    const int KB = K >> 5;
    const int lane = threadIdx.x & 63;
    const int wid = threadIdx.x >> 6;
    const int lm = lane & 15, lq = lane >> 4;
    const int m0 = blockIdx.x * 128 + wid * 32;
    const int n0t = blockIdx.y * NT_N;

    const float* arow[2];
    const float* brow[2];
#pragma unroll
    for (int mt = 0; mt < 2; mt++) {
        int row = m0 + mt * 16 + lm;
        if (FUSEA) {
            int b = row / (NQ * NQ);
            int rr = row - b * (NQ * NQ);
            int i = rr / NQ;
            int j = rr - i * NQ;
            arow[mt] = FA + (size_t)(b * NQ + i) * 256;
            brow[mt] = FB + (size_t)(b * NQ + j) * 256;
        } else if (GATHA) {
            arow[mt] = A + (size_t)gmap[row] * K;
        } else if (LISTM) {
            int lr = listm[row];
            lr = ((unsigned)lr < (unsigned)NN) ? lr : 0;
            arow[mt] = A + (size_t)lr * K;
        } else {
            arow[mt] = A + (size_t)row * K;
        }
    }

    floatx4 acc[2][NT_N];
#pragma unroll
    for (int mt = 0; mt < 2; mt++)
#pragma unroll
        for (int nt = 0; nt < NT_N; nt++) acc[mt][nt] = (floatx4)0.f;

    for (int kb = 0; kb < KB; kb++) {
        const int k0 = kb * 32 + lq * 8;
        half8 ahi[2], alo[2];
#pragma unroll
        for (int mt = 0; mt < 2; mt++) {
            floatx4 av0, av1;
            if (FUSEA) {
                floatx4 fa0 = *(const floatx4*)(arow[mt] + k0);
                floatx4 fa1 = *(const floatx4*)(arow[mt] + k0 + 4);
                floatx4 fb0 = *(const floatx4*)(brow[mt] + k0);
                floatx4 fb1 = *(const floatx4*)(brow[mt] + k0 + 4);
#pragma unroll
                for (int q = 0; q < 4; q++) {
                    av0[q] = lrelu(fa0[q] + fb0[q]);
                    av1[q] = lrelu(fa1[q] + fb1[q]);
                }
            } else {
                av0 = *(const floatx4*)(arow[mt] + k0);
                av1 = *(const floatx4*)(arow[mt] + k0 + 4);
            }
#pragma unroll
            for (int q = 0; q < 4; q++) {
                _Float16 h0 = (_Float16)av0[q];
                ahi[mt][q] = h0;
                alo[mt][q] = (_Float16)(av0[q] - (float)h0);
                _Float16 h1 = (_Float16)av1[q];
                ahi[mt][4 + q] = h1;
                alo[mt][4 + q] = (_Float16)(av1[q] - (float)h1);
            }
        }
#pragma unroll
        for (int nt = 0; nt < NT_N; nt++) {
            size_t boff = (((size_t)(n0t + nt) * KB + kb) * 64 + lane) * 8;
            half8 bhi = *(const half8*)(Bh + boff);
            half8 blo = *(const half8*)(Bl + boff);
#pragma unroll
            for (int mt = 0; mt < 2; mt++) {
                acc[mt][nt] = __builtin_amdgcn_mfma_f32_16x16x32_f16(ahi[mt], bhi, acc[mt][nt], 0, 0, 0);
                acc[mt][nt] = __builtin_amdgcn_mfma_f32_16x16x32_f16(ahi[mt], blo, acc[mt][nt], 0, 0, 0);
                acc[mt][nt] = __builtin_amdgcn_mfma_f32_16x16x32_f16(alo[mt], bhi, acc[mt][nt], 0, 0, 0);
            }
        }
    }

    // store-row mapping (C/D layout: col=lane&15, row=(lane>>4)*4+reg)
    int strow[2][4];
    bool svalid[2][4];
#pragma unroll
    for (int mt = 0; mt < 2; mt++)
#pragma unroll
        for (int r = 0; r < 4; r++) {
            int mlog = m0 + mt * 16 + lq * 4 + r;
            if (LISTM) {
                int sr = listm[mlog];
                svalid[mt][r] = (unsigned)sr < (unsigned)NN;
                strow[mt][r] = svalid[mt][r] ? sr : 0;
            } else {
                svalid[mt][r] = true;
                strow[mt][r] = mlog;
            }
        }

#pragma unroll
    for (int nt = 0; nt < NT_N; nt++) {
        int col = (n0t + nt) * 16 + lm;
        float bv = (BIAS || P0SPLIT) ? bias[col < 256 ? col : 0] : 0.f;
#pragma unroll
        for (int mt = 0; mt < 2; mt++) {
#pragma unroll
            for (int r = 0; r < 4; r++) {
                if (!svalid[mt][r]) continue;
                int row = strow[mt][r];
                float val = acc[mt][nt][r];
                if (P0SPLIT) {
                    if (col < 256) C[(size_t)row * 256 + col] = val + bv;
                    else C2[(size_t)row * 256 + col - 256] = val;
                } else {
                    if (BIAS) val += bv;
                    if (LEAKY) val = lrelu(val);
                    C[(size_t)row * N + col] = val;
                }
            }
        }
    }
}

// ---------------- FUSED GCN layer: aggregate-then-GEMM (A·h)·W ----------------
// 16-slot blocks: phase A is a SINGLE pass (8 groups x 2 slots), writing packed
// hi/lo rows into LDS X, raw residual rows into LDS R, node ids into NID.
// Phase B: 4 waves compute the same 16 rows over disjoint 32-col slices
// (nt = wid*2+{0,1}), K=128; bias + (leaky) + residual from R.
// FINAL: instead of storing hq to global, repack rows into X and run phase C —
// the combined-mw0 P0 GEMM (K=128, N=512) writing Abuf (+mb0) / Bbuf directly.
template <bool LEAKY, bool FINAL>
__launch_bounds__(256, 8)
__global__ void k_lagg(const float* __restrict__ in, float* __restrict__ outp,
                       const int4* __restrict__ rec, const int2* __restrict__ csre,
                       const int* __restrict__ cntp, int fixcnt,
                       const _Float16* __restrict__ Bh, const _Float16* __restrict__ Bl,
                       const float* __restrict__ bias,
                       const _Float16* __restrict__ BhP, const _Float16* __restrict__ BlP,
                       const float* __restrict__ mb0p,
                       float* __restrict__ Abuf, float* __restrict__ Bbuf) {
    int lcnt = cntp ? *cntp : fixcnt;
    int sbase = blockIdx.x * 16;
    if (sbase >= lcnt) return;
    __shared__ uint X[16][132];
    __shared__ float R[16][132];
    __shared__ int NID[16];
    int tid = threadIdx.x;
    int sl = tid & 31;
    int grp = tid >> 5;
    const float4* in4 = (const float4*)in;
    // ---- phase A: aggregate 16 rows, one pass (8 groups x 2 slots) ----
    {
        int lrow0 = grp * 2;
        int p0i = sbase + lrow0, p1i = p0i + 1;
        bool val0 = p0i < lcnt, val1 = p1i < lcnt;
        const int4* r0p = rec + (size_t)(val0 ? p0i : 0) * 4;
        const int4* r1p = rec + (size_t)(val1 ? p1i : 0) * 4;
        int4 hd0 = r0p[0], ea0 = r0p[1], eb0 = r0p[2], ec0 = r0p[3];
        int4 hd1 = r1p[0], ea1 = r1p[1], eb1 = r1p[2], ec1 = r1p[3];
        int n0 = hd0.x - 1;
        int n1 = hd1.x - 1;
        if (sl == 0) {
            NID[lrow0] = n0;
            NID[lrow0 + 1] = n1;
        }
        float s20 = __int_as_float(hd0.z), s21 = __int_as_float(hd1.z);
        float4 v0  = in4[(size_t)n0 * 32 + sl];
        float4 v1  = in4[(size_t)n1 * 32 + sl];
        float4 u00 = in4[(size_t)ea0.x * 32 + sl];
        float4 u01 = in4[(size_t)ea0.z * 32 + sl];
        float4 u02 = in4[(size_t)eb0.x * 32 + sl];
        float4 u03 = in4[(size_t)eb0.z * 32 + sl];
        float4 u04 = in4[(size_t)ec0.x * 32 + sl];
        float4 u05 = in4[(size_t)ec0.z * 32 + sl];
        float4 u10 = in4[(size_t)ea1.x * 32 + sl];
        float4 u11 = in4[(size_t)ea1.z * 32 + sl];
        float4 u12 = in4[(size_t)eb1.x * 32 + sl];
        float4 u13 = in4[(size_t)eb1.z * 32 + sl];
        float4 u14 = in4[(size_t)ec1.x * 32 + sl];
        float4 u15 = in4[(size_t)ec1.z * 32 + sl];
        // stash raw residual rows for phase B
        *(float4*)&R[lrow0][sl * 4] = v0;
        *(float4*)&R[lrow0 + 1][sl * 4] = v1;
        float w00 = __int_as_float(ea0.y), w01 = __int_as_float(ea0.w);
        float w02 = __int_as_float(eb0.y), w03 = __int_as_float(eb0.w);
        float w04 = __int_as_float(ec0.y), w05 = __int_as_float(ec0.w);
        float w10 = __int_as_float(ea1.y), w11 = __int_as_float(ea1.w);
        float w12 = __int_as_float(eb1.y), w13 = __int_as_float(eb1.w);
        float w14 = __int_as_float(ec1.y), w15 = __int_as_float(ec1.w);
        float a0x = v0.x * s20 + u00.x * w00 + u01.x * w01 + u02.x * w02 + u03.x * w03 + u04.x * w04 + u05.x * w05;
        float a0y = v0.y * s20 + u00.y * w00 + u01.y * w01 + u02.y * w02 + u03.y * w03 + u04.y * w04 + u05.y * w05;
        float a0z = v0.z * s20 + u00.z * w00 + u01.z * w01 + u02.z * w02 + u03.z * w03 + u04.z * w04 + u05.z * w05;
        float a0w = v0.w * s20 + u00.w * w00 + u01.w * w01 + u02.w * w02 + u03.w * w03 + u04.w * w04 + u05.w * w05;
        float a1x = v1.x * s21 + u10.x * w10 + u11.x * w11 + u12.x * w12 + u13.x * w13 + u14.x * w14 + u15.x * w15;
        float a1y = v1.y * s21 + u10.y * w10 + u11.y * w11 + u12.y * w12 + u13.y * w13 + u14.y * w14 + u15.y * w15;
        float a1z = v1.z * s21 + u10.z * w10 + u11.z * w11 + u12.z * w12 + u13.z * w13 + u14.z * w14 + u15.z * w15;
        float a1w = v1.w * s21 + u10.w * w10 + u11.w * w11 + u12.w * w12 + u13.w * w13 + u14.w * w14 + u15.w * w15;
        int deg0 = val0 ? hd0.y : 0, deg1 = val1 ? hd1.y : 0;
        int dm = max(deg0, deg1);
        if (dm > 6) {
            // rare overflow path: clamped CSR loop for edges >= 6
            int off0 = hd0.w, off1 = hd1.w;
            int d0c = max(deg0 - 1, 0), d1c = max(deg1 - 1, 0);
            for (int e = 6; e < dm; e += 6) {
                int2 e00 = csre[off0 + min(e,     d0c)];
                int2 e01 = csre[off0 + min(e + 1, d0c)];
                int2 e02 = csre[off0 + min(e + 2, d0c)];
                int2 e03 = csre[off0 + min(e + 3, d0c)];
                int2 e04 = csre[off0 + min(e + 4, d0c)];
                int2 e05 = csre[off0 + min(e + 5, d0c)];
                int2 e10 = csre[off1 + min(e,     d1c)];
                int2 e11 = csre[off1 + min(e + 1, d1c)];
                int2 e12 = csre[off1 + min(e + 2, d1c)];
                int2 e13 = csre[off1 + min(e + 3, d1c)];
                int2 e14 = csre[off1 + min(e + 4, d1c)];
                int2 e15 = csre[off1 + min(e + 5, d1c)];
                float4 x00 = in4[(size_t)e00.x * 32 + sl];
                float4 x01 = in4[(size_t)e01.x * 32 + sl];
                float4 x02 = in4[(size_t)e02.x * 32 + sl];
                float4 x03 = in4[(size_t)e03.x * 32 + sl];
                float4 x04 = in4[(size_t)e04.x * 32 + sl];
                float4 x05 = in4[(size_t)e05.x * 32 + sl];
                float4 x10 = in4[(size_t)e10.x * 32 + sl];
                float4 x11 = in4[(size_t)e11.x * 32 + sl];
                float4 x12 = in4[(size_t)e12.x * 32 + sl];
                float4 x13 = in4[(size_t)e13.x * 32 + sl];
                float4 x14 = in4[(size_t)e14.x * 32 + sl];
                float4 x15 = in4[(size_t)e15.x * 32 + sl];
                float q00 = (e     < deg0) ? __int_as_float(e00.y) : 0.f;
                float q01 = (e + 1 < deg0) ? __int_as_float(e01.y) : 0.f;
                float q02 = (e + 2 < deg0) ? __int_as_float(e02.y) : 0.f;
                float q03 = (e + 3 < deg0) ? __int_as_float(e03.y) : 0.f;
                float q04 = (e + 4 < deg0) ? __int_as_float(e04.y) : 0.f;
                float q05 = (e + 5 < deg0) ? __int_as_float(e05.y) : 0.f;
                float q10 = (e     < deg1) ? __int_as_float(e10.y) : 0.f;
                float q11 = (e + 1 < deg1) ? __int_as_float(e11.y) : 0.f;
                float q12 = (e + 2 < deg1) ? __int_as_float(e12.y) : 0.f;
                float q13 = (e + 3 < deg1) ? __int_as_float(e13.y) : 0.f;
                float q14 = (e + 4 < deg1) ? __int_as_float(e14.y) : 0.f;
                float q15 = (e + 5 < deg1) ? __int_as_float(e15.y) : 0.f;
                a0x += x00.x * q00 + x01.x * q01 + x02.x * q02 + x03.x * q03 + x04.x * q04 + x05.x * q05;
                a0y += x00.y * q00 + x01.y * q01 + x02.y * q02 + x03.y * q03 + x04.y * q04 + x05.y * q05;
                a0z += x00.z * q00 + x01.z * q01 + x02.z * q02 + x03.z * q03 + x04.z * q04 + x05.z * q05;
                a0w += x00.w * q00 + x01.w * q01 + x02.w * q02 + x03.w * q03 + x04.w * q04 + x05.w * q05;
                a1x += x10.x * q10 + x11.x * q11 + x12.x * q12 + x13.x * q13 + x14.x * q14 + x15.x * q15;
                a1y += x10.y * q10 + x11.y * q11 + x12.y * q12 + x13.y * q13 + x14.y * q14 + x15.y * q15;
                a1z += x10.z * q10 + x11.z * q11 + x12.z * q12 + x13.z * q13 + x14.z * q14 + x15.z * q15;
                a1w += x10.w * q10 + x11.w * q11 + x12.w * q12 + x13.w * q13 + x14.w * q14 + x15.w * q15;
            }
        }
        *(uint4*)&X[lrow0][sl * 4] =
            make_uint4(packhl(a0x), packhl(a0y), packhl(a0z), packhl(a0w));
        *(uint4*)&X[lrow0 + 1][sl * 4] =
            make_uint4(packhl(a1x), packhl(a1y), packhl(a1z), packhl(a1w));
    }
    __syncthreads();
    // ---- phase B: 4 waves, same 16 rows, disjoint 32-col slices; K=128 ----
    const int lane = tid & 63;
    const int wid = tid >> 6;
    const int lm = lane & 15, lq = lane >> 4;
    floatx4 acc[2];
    acc[0] = (floatx4)0.f;
    acc[1] = (floatx4)0.f;
#pragma unroll
    for (int kb = 0; kb < 4; kb++) {
        const int k0 = kb * 32 + lq * 8;
        uint4 pa = *(const uint4*)&X[lm][k0];
        uint4 pb = *(const uint4*)&X[lm][k0 + 4];
        half8 ahi, alo;
        unpack8(pa, pb, ahi, alo);
#pragma unroll
        for (int ntl = 0; ntl < 2; ntl++) {
            int nt = wid * 2 + ntl;
            size_t boff = (((size_t)nt * 4 + kb) * 64 + lane) * 8;
            half8 bhi = *(const half8*)(Bh + boff);
            half8 blo = *(const half8*)(Bl + boff);
            acc[ntl] = __builtin_amdgcn_mfma_f32_16x16x32_f16(ahi, bhi, acc[ntl], 0, 0, 0);
            acc[ntl] = __builtin_amdgcn_mfma_f32_16x16x32_f16(ahi, blo, acc[ntl], 0, 0, 0);
            acc[ntl] = __builtin_amdgcn_mfma_f32_16x16x32_f16(alo, bhi, acc[ntl], 0, 0, 0);
        }
    }
    if (FINAL) __syncthreads();   // all phase-B X reads done before X overwrite
    // ---- C-write: bias + (leaky) + residual from R ----
    int nodes[4];
    bool sval[4];
#pragma unroll
    for (int r = 0; r < 4; r++) {
        int slot = sbase + lq * 4 + r;
        sval[r] = slot < lcnt;
        nodes[r] = NID[lq * 4 + r];
    }
#pragma unroll
    for (int ntl = 0; ntl < 2; ntl++) {
        int col = (wid * 2 + ntl) * 16 + lm;
        float bv = bias[col];
#pragma unroll
        for (int r = 0; r < 4; r++) {
            if (!sval[r]) continue;
            float val = acc[ntl][r] + bv;
            if (LEAKY) val = lrelu(val);
            val += R[lq * 4 + r][col];
            if (FINAL)
                X[lq * 4 + r][col] = packhl(val);   // hq row stays in LDS
            else
                outp[(size_t)nodes[r] * FEAT + col] = val;
        }
    }
    // ---- phase C (FINAL only): P0 GEMM, K=128 N=512, write Abuf/Bbuf ----
    if (FINAL) {
        __syncthreads();
#pragma unroll
        for (int c = 0; c < 2; c++) {
            floatx4 acc4[4];
#pragma unroll
            for (int nt = 0; nt < 4; nt++) acc4[nt] = (floatx4)0.f;
#pragma unroll
            for (int kb = 0; kb < 4; kb++) {
                const int k0 = kb * 32 + lq * 8;
                uint4 pa = *(const uint4*)&X[lm][k0];
                uint4 pb = *(const uint4*)&X[lm][k0 + 4];
                half8 ahi, alo;
                unpack8(pa, pb, ahi, alo);
#pragma unroll
                for (int nt = 0; nt < 4; nt++) {
                    int T = wid * 8 + c * 4 + nt;
                    size_t boff = (((size_t)T * 4 + kb) * 64 + lane) * 8;
                    half8 bhi = *(const half8*)(BhP + boff);
                    half8 blo = *(const half8*)(BlP + boff);
                    acc4[nt] = __builtin_amdgcn_mfma_f32_16x16x32_f16(ahi, bhi, acc4[nt], 0, 0, 0);
                    acc4[nt] = __builtin_amdgcn_mfma_f32_16x16x32_f16(ahi, blo, acc4[nt], 0, 0, 0);
                    acc4[nt] = __builtin_amdgcn_mfma_f32_16x16x32_f16(alo, bhi, acc4[nt], 0, 0, 0);
                }
            }
#pragma unroll
            for (int nt = 0; nt < 4; nt++) {
                int T = wid * 8 + c * 4 + nt;
                int col = T * 16 + lm;
#pragma unroll
                for (int r = 0; r < 4; r++) {
                    int q = sbase + lq * 4 + r;
                    float val = acc4[nt][r];
                    if (col < 256) Abuf[(size_t)q * 256 + col] = val + mb0p[col];
                    else Bbuf[(size_t)q * 256 + col - 256] = val;
                }
            }
        }
    }
}

// ---------------- fused pair MLP: wave-local in-place LDS, no barriers ----------------
template <int KB, int NT>
__device__ __forceinline__ void pair_stage(uint (*__restrict__ X)[132],
                                           const _Float16* __restrict__ Bh,
                                           const _Float16* __restrict__ Bl,
                                           const float* __restrict__ bias,
                                           int srow, int lane) {
    const int lm = lane & 15, lq = lane >> 4;
    floatx4 acc[NT];
#pragma unroll
    for (int nt = 0; nt < NT; nt++) acc[nt] = (floatx4)0.f;
#pragma unroll
    for (int kb = 0; kb < KB; kb++) {
        const int k0 = kb * 32 + lq * 8;
        uint4 pa = *(const uint4*)&X[srow + lm][k0];
        uint4 pb = *(const uint4*)&X[srow + lm][k0 + 4];
        half8 ahi, alo;
        unpack8(pa, pb, ahi, alo);
#pragma unroll
        for (int nt = 0; nt < NT; nt++) {
            size_t boff = (((size_t)nt * KB + kb) * 64 + lane) * 8;
            half8 bhi = *(const half8*)(Bh + boff);
            half8 blo = *(const half8*)(Bl + boff);
            acc[nt] = __builtin_amdgcn_mfma_f32_16x16x32_f16(ahi, bhi, acc[nt], 0, 0, 0);
            acc[nt] = __builtin_amdgcn_mfma_f32_16x16x32_f16(ahi, blo, acc[nt], 0, 0, 0);
            acc[nt] = __builtin_amdgcn_mfma_f32_16x16x32_f16(alo, bhi, acc[nt], 0, 0, 0);
        }
    }
#pragma unroll
    for (int nt = 0; nt < NT; nt++) {
        int col = nt * 16 + lm;
        float bv = bias[col];
#pragma unroll
        for (int r = 0; r < 4; r++) {
            X[srow + lq * 4 + r][col] = packhl(lrelu(acc[nt][r] + bv));
        }
    }
}

__launch_bounds__(256, 4)
__global__ void k_pair(const float* __restrict__ FA, const float* __restrict__ FB,
                       const _Float16* __restrict__ bth, const _Float16* __restrict__ btl,
                       const float* __restrict__ mb1, const float* __restrict__ mb2,
                       const float* __restrict__ mb3, const float* __restrict__ mb4,
                       const float* __restrict__ mw5, const float* __restrict__ mb5,
                       float* __restrict__ out) {
    __shared__ uint X[64][132];
    const int lane = threadIdx.x & 63;
    const int wid = threadIdx.x >> 6;
    const int lm = lane & 15, lq = lane >> 4;
    const int srow = wid * 16;
    const int rbase = blockIdx.x * 64;

    // ---- stage 1 (M1): K=256 via fused concat(h_i,h_j)+lrelu, N=128 -> X ----
    {
        const int grow = rbase + srow + lm;
        int b = grow / (NQ * NQ);
        int rr = grow - b * (NQ * NQ);
        int i = rr / NQ;
        int j = rr - i * NQ;
        const float* arow = FA + (size_t)(b * NQ + i) * 256;
        const float* brow = FB + (size_t)(b * NQ + j) * 256;
        const _Float16* Bh = bth + OFF_M1;
        const _Float16* Bl = btl + OFF_M1;
        floatx4 acc[8];
#pragma unroll
        for (int nt = 0; nt < 8; nt++) acc[nt] = (floatx4)0.f;
        const int KB = 8;
#pragma unroll
        for (int kb = 0; kb < KB; kb++) {
            const int k0 = kb * 32 + lq * 8;
            floatx4 fa0 = *(const floatx4*)(arow + k0);
            floatx4 fa1 = *(const floatx4*)(arow + k0 + 4);
            floatx4 fb0 = *(const floatx4*)(brow + k0);
            floatx4 fb1 = *(const floatx4*)(brow + k0 + 4);
            half8 ahi, alo;
#pragma unroll
            for (int q = 0; q < 4; q++) {
                float v0 = lrelu(fa0[q] + fb0[q]);
                float v1 = lrelu(fa1[q] + fb1[q]);
                _Float16 h0 = (_Float16)v0;
                ahi[q] = h0;
                alo[q] = (_Float16)(v0 - (float)h0);
                _Float16 h1 = (_Float16)v1;
                ahi[4 + q] = h1;
                alo[4 + q] = (_Float16)(v1 - (float)h1);
            }
#pragma unroll
            for (int nt = 0; nt < 8; nt++) {
                size_t boff = (((size_t)nt * KB + kb) * 64 + lane) * 8;
                half8 bhi = *(const half8*)(Bh + boff);
                half8 blo = *(const half8*)(Bl + boff);
                acc[nt] = __builtin_amdgcn_mfma_f32_16x16x32_f16(ahi, bhi, acc[nt], 0, 0, 0);
                acc[nt] = __builtin_amdgcn_mfma_f32_16x16x32_f16(ahi, blo, acc[nt], 0, 0, 0);
                acc[nt] = __builtin_amdgcn_mfma_f32_16x16x32_f16(alo, bhi, acc[nt], 0, 0, 0);
            }
        }
#pragma unroll
        for (int nt = 0; nt < 8; nt++) {
            int col = nt * 16 + lm;
            float bv = mb1[col];
#pragma unroll
            for (int r = 0; r < 4; r++) {
                X[srow + lq * 4 + r][col] = packhl(lrelu(acc[nt][r] + bv));
            }
        }
    }
    // ---- stage 2 (M2): K=128 N=128, in place ----
    pair_stage<4, 8>(X, bth + OFF_M2, btl + OFF_M2, mb2, srow, lane);
    // ---- stage 3 (M3): K=128 N=64, in place ----
    pair_stage<4, 4>(X, bth + OFF_M3, btl + OFF_M3, mb3, srow, lane);
    // ---- stage 4 (M4): K=64 N=64, in place ----
    pair_stage<2, 4>(X, bth + OFF_M4, btl + OFF_M4, mb4, srow, lane);
    // ---- stage 5 (M5): dot-64 per row + atomic symmetrize into out ----
    {
        int row = srow + (lane >> 2);
        int part = lane & 3;
        float s = 0.f;
#pragma unroll
        for (int c4 = 0; c4 < 4; c4++) {
            int c0 = part * 16 + c4 * 4;
            uint4 u = *(const uint4*)&X[row][c0];
            const float* wp = mw5 + c0;
            uint uu[4] = {u.x, u.y, u.z, u.w};
#pragma unroll
            for (int q = 0; q < 4; q++) {
                union { unsigned short us; _Float16 f; } ch, cl;
                ch.us = (unsigned short)(uu[q] & 0xffffu);
                cl.us = (unsigned short)(uu[q] >> 16);
                s += ((float)ch.f + (float)cl.f) * wp[q];
            }
        }
        s += __shfl_xor(s, 1);
        s += __shfl_xor(s, 2);
        if (part == 0) {
            int p = rbase + row;
            int b = p / (NQ * NQ);
            int rr = p - b * (NQ * NQ);
            int i = rr / NQ, j = rr - i * NQ;
            float hv = 0.5f * (s + mb5[0]);
            atomicAdd(&out[(size_t)b * NQ * NQ + i * NQ + j], hv);
            atomicAdd(&out[(size_t)b * NQ * NQ + j * NQ + i], hv);
        }
    }
}

// ---------------- layer-0 aggregation from the L2-resident token table ----------------
__global__ void k_agg0(const float* __restrict__ embW, const float* __restrict__ emb,
                       float* __restrict__ h,
                       const int4* __restrict__ meta, const int2* __restrict__ csre0,
                       const float* __restrict__ bias) {
    int tid = threadIdx.x;
    int sl = tid & 31;
    int p = blockIdx.x * 8 + (tid >> 5);
    int n0 = p * 2, n1 = n0 + 1;
    int4 m0 = meta[n0], m1 = meta[n1];
    float di0 = __int_as_float(m0.z), di1 = __int_as_float(m1.z);
    int off0 = m0.x, deg0 = m0.y;
    int off1 = m1.x, deg1 = m1.y;
    float4 v0 = ((const float4*)(embW + (size_t)m0.w * FEAT))[sl];
    float4 v1 = ((const float4*)(embW + (size_t)m1.w * FEAT))[sl];
    float4 ho0 = ((const float4*)(emb + (size_t)m0.w * FEAT))[sl];
    float4 ho1 = ((const float4*)(emb + (size_t)m1.w * FEAT))[sl];
    float s20 = di0 * di0, s21 = di1 * di1;
    float a0x = v0.x * s20, a0y = v0.y * s20, a0z = v0.z * s20, a0w = v0.w * s20;
    float a1x = v1.x * s21, a1y = v1.y * s21, a1z = v1.z * s21, a1w = v1.w * s21;
    int d0c = max(deg0 - 1, 0), d1c = max(deg1 - 1, 0);
    int dm = max(deg0, deg1);
    for (int e = 0; e < dm; e += 4) {
        int2 e00 = csre0[off0 + min(e,     d0c)];
        int2 e01 = csre0[off0 + min(e + 1, d0c)];
        int2 e02 = csre0[off0 + min(e + 2, d0c)];
        int2 e03 = csre0[off0 + min(e + 3, d0c)];
        int2 e10 = csre0[off1 + min(e,     d1c)];
        int2 e11 = csre0[off1 + min(e + 1, d1c)];
        int2 e12 = csre0[off1 + min(e + 2, d1c)];
        int2 e13 = csre0[off1 + min(e + 3, d1c)];
        float4 u00 = ((const float4*)(embW + (size_t)e00.x * FEAT))[sl];
        float4 u01 = ((const float4*)(embW + (size_t)e01.x * FEAT))[sl];
        float4 u02 = ((const float4*)(embW + (size_t)e02.x * FEAT))[sl];
        float4 u03 = ((const float4*)(embW + (size_t)e03.x * FEAT))[sl];
        float4 u10 = ((const float4*)(embW + (size_t)e10.x * FEAT))[sl];
        float4 u11 = ((const float4*)(embW + (size_t)e11.x * FEAT))[sl];
        float4 u12 = ((const float4*)(embW + (size_t)e12.x * FEAT))[sl];
        float4 u13 = ((const float4*)(embW + (size_t)e13.x * FEAT))[sl];
        float w00 = (e     < deg0) ? __int_as_float(e00.y) : 0.f;
        float w01 = (e + 1 < deg0) ? __int_as_float(e01.y) : 0.f;
        float w02 = (e + 2 < deg0) ? __int_as_float(e02.y) : 0.f;
        float w03 = (e + 3 < deg0) ? __int_as_float(e03.y) : 0.f;
        float w10 = (e     < deg1) ? __int_as_float(e10.y) : 0.f;
        float w11 = (e + 1 < deg1) ? __int_as_float(e11.y) : 0.f;
        float w12 = (e + 2 < deg1) ? __int_as_float(e12.y) : 0.f;
        float w13 = (e + 3 < deg1) ? __int_as_float(e13.y) : 0.f;
        a0x += u00.x * w00 + u01.x * w01 + u02.x * w02 + u03.x * w03;
        a0y += u00.y * w00 + u01.y * w01 + u02.y * w02 + u03.y * w03;
        a0z += u00.z * w00 + u01.z * w01 + u02.z * w02 + u03.z * w03;
        a0w += u00.w * w00 + u01.w * w01 + u02.w * w02 + u03.w * w03;
        a1x += u10.x * w10 + u11.x * w11 + u12.x * w12 + u13.x * w13;
        a1y += u10.y * w10 + u11.y * w11 + u12.y * w12 + u13.y * w13;
        a1z += u10.z * w10 + u11.z * w11 + u12.z * w12 + u13.z * w13;
        a1w += u10.w * w10 + u11.w * w11 + u12.w * w12 + u13.w * w13;
    }
    float4 bv = ((const float4*)bias)[sl];
    float4 r0, r1;
    r0.x = lrelu(a0x + bv.x) + ho0.x;
    r0.y = lrelu(a0y + bv.y) + ho0.y;
    r0.z = lrelu(a0z + bv.z) + ho0.z;
    r0.w = lrelu(a0w + bv.w) + ho0.w;
    r1.x = lrelu(a1x + bv.x) + ho1.x;
    r1.y = lrelu(a1y + bv.y) + ho1.y;
    r1.z = lrelu(a1z + bv.z) + ho1.z;
    r1.w = lrelu(a1w + bv.w) + ho1.w;
    ((float4*)(h + (size_t)n0 * FEAT))[sl] = r0;
    ((float4*)(h + (size_t)n1 * FEAT))[sl] = r1;
}

extern "C" void kernel_launch(void* const* d_in, const int* in_sizes, int n_in,
                              void* d_out, int out_size, void* d_ws, size_t ws_size,
                              hipStream_t stream) {
    const int* x = (const int*)d_in[0];
    const int* ei = (const int*)d_in[1];
    const int* e_src = ei;
    const int* e_dst = ei + NE;
    const float* emb = (const float*)d_in[2];
    const float* gw = (const float*)d_in[3];   // [5,128,128]
    const float* gb = (const float*)d_in[4];   // [5,128]
    const float* mw0 = (const float*)d_in[5];
    const float* mb0 = (const float*)d_in[6];
    const float* mw1 = (const float*)d_in[7];
    const float* mb1 = (const float*)d_in[8];
    const float* mw2 = (const float*)d_in[9];
    const float* mb2 = (const float*)d_in[10];
    const float* mw3 = (const float*)d_in[11];
    const float* mb3 = (const float*)d_in[12];
    const float* mw4 = (const float*)d_in[13];
    const float* mb4 = (const float*)d_in[14];
    const float* mw5 = (const float*)d_in[15];
    const float* mb5 = (const float*)d_in[16];
    float* out = (float*)d_out;

    float* wsf = (float*)d_ws;
    size_t o = 0;
    const size_t HSZ = (size_t)NN * FEAT;             // 16,711,680
    float* h  = wsf + o; o += HSZ;    // layer ping buffer
    float* hw = wsf + o; o += HSZ;    // layer pong buffer
    // zero-memset region: cnt, fill, flag1, flag2, flag3, cursors (contiguous)
    int* cnt   = (int*)(wsf + o); o += NN;
    int* fill  = (int*)(wsf + o); o += NN;
    int* flag1 = (int*)(wsf + o); o += NN;
    int* flag2 = (int*)(wsf + o); o += NN;
    int* flag3 = (int*)(wsf + o); o += NN;
    int* curs  = (int*)(wsf + o); o += 16;   // [0]=offs [1]=S1 [2]=S2 [3]=S3
    int* offs = (int*)(wsf + o); o += NN;
    float* dinv = wsf + o; o += NN;
    int4* meta = (int4*)(wsf + o); o += 4 * (size_t)NN;
    int2* csre  = (int2*)(wsf + o); o += 2 * (size_t)(NE + 8);  // +8 slop for deg-0 clamp
    int2* csre0 = (int2*)(wsf + o); o += 2 * (size_t)(NE + 8);  // token edges
    int* idmap = (int*)(wsf + o); o += 1024;
    float* embW = wsf + o; o += (size_t)1024 * FEAT;          // emb@W0 table
    float* Abuf = wsf + o; o += (size_t)BATCH * NQ * 256;     // 655,360
    float* Bbuf = wsf + o; o += (size_t)BATCH * NQ * 256;     // 655,360
    // packed agg records: 64B per node per list (no memset; validity via cursors)
    int4* rec1 = (int4*)(wsf + o); o += 16 * (size_t)NN;
    int4* rec2 = (int4*)(wsf + o); o += 16 * (size_t)NN;
    int4* rec3 = (int4*)(wsf + o); o += 16 * (size_t)NN;
    int4* rec0 = (int4*)(wsf + o); o += 16 * (size_t)(BATCH * NQ);
    _Float16* bt_hi = (_Float16*)(wsf + o); o += (TS_TOTAL + 2) / 2;
    _Float16* bt_lo = (_Float16*)(wsf + o); o += (TS_TOTAL + 2) / 2;

    // --- zero output (k_pair accumulates symmetrized halves atomically) ---
    hipMemsetAsync(out, 0, (size_t)NPAIR * sizeof(float), stream);

    // --- weight transpose+split+pack ---
    k_tsplit_all<<<TS_TOTAL / 256, 256, 0, stream>>>(gw, mw0, mw1, mw2, mw3, mw4, bt_hi, bt_lo);

    // --- CSR build + cone records S1/S2/S3 + rec0 (folded into first s1pass) ---
    hipMemsetAsync(cnt, 0, (5 * NN + 16) * sizeof(int), stream); // cnt+fill+flags+cursors
    hipMemsetAsync(csre + NE, 0, 8 * sizeof(int2), stream);      // slop
    hipMemsetAsync(csre0 + NE, 0, 8 * sizeof(int2), stream);     // slop
    k_count<<<NE / 256, 256, 0, stream>>>(e_dst, cnt);
    k_offsets<<<NB, 256, 0, stream>>>(cnt, x, offs, dinv, meta, curs + 0, flag1, idmap);
    k_fill<<<NE / 256, 256, 0, stream>>>(e_src, e_dst, offs, fill, dinv, x, csre, csre0, flag1);
    k_s1pass<<<NB + (BATCH * NQ + 255) / 256, 256, 0, stream>>>(
        flag1, meta, csre, curs + 1, rec1, flag2, rec0);                     // S1 + mark S2 + rec0
    k_s1pass<<<NB, 256, 0, stream>>>(flag2, meta, csre, curs + 2, rec2, flag3, nullptr);   // S2 + mark S3
    k_s1pass<<<NB, 256, 0, stream>>>(flag3, meta, csre, curs + 3, rec3, nullptr, nullptr); // S3

    // --- layer 0 via token table: embW = emb@W0 (1021 rows, clamped id map) ---
    hgemm<1, false, false, false, false, true, false><<<dim3(8, 8), 256, 0, stream>>>(
        emb, nullptr, nullptr, bt_hi + OFF_GCN, bt_lo + OFF_GCN,
        nullptr, embW, nullptr, FEAT, FEAT, idmap, nullptr);
    k_agg0<<<NN / 16, 256, 0, stream>>>(embW, emb, h, meta, csre0, gb + 0 * FEAT);

    // --- fused GCN layers: aggregate-then-GEMM, ping-pong h <-> hw ---
    // L1 @S3: h -> hw
    k_lagg<true, false><<<NN / 16, 256, 0, stream>>>(
        h, hw, rec3, csre, curs + 3, 0,
        bt_hi + OFF_GCN + 1 * 16384, bt_lo + OFF_GCN + 1 * 16384, gb + 1 * FEAT,
        nullptr, nullptr, nullptr, nullptr, nullptr);
    // L2 @S2: hw -> h
    k_lagg<true, false><<<NN / 16, 256, 0, stream>>>(
        hw, h, rec2, csre, curs + 2, 0,
        bt_hi + OFF_GCN + 2 * 16384, bt_lo + OFF_GCN + 2 * 16384, gb + 2 * FEAT,
        nullptr, nullptr, nullptr, nullptr, nullptr);
    // L3 @S1: h -> hw
    k_lagg<true, false><<<NN / 16, 256, 0, stream>>>(
        h, hw, rec1, csre, curs + 1, 0,
        bt_hi + OFF_GCN + 3 * 16384, bt_lo + OFF_GCN + 3 * 16384, gb + 3 * FEAT,
        nullptr, nullptr, nullptr, nullptr, nullptr);
    // L4 @S0 (dense, no leaky) + fused P0: hw -> Abuf/Bbuf directly
    k_lagg<false, true><<<(BATCH * NQ) / 16, 256, 0, stream>>>(
        hw, nullptr, rec0, csre, nullptr, BATCH * NQ,
        bt_hi + OFF_GCN + 4 * 16384, bt_lo + OFF_GCN + 4 * 16384, gb + 4 * FEAT,
        bt_hi + OFF_P0, bt_lo + OFF_P0, mb0, Abuf, Bbuf);

    // --- fused pair MLP M1..M5 + atomic symmetrize -> out ---
    k_pair<<<NPAIR / 64, 256, 0, stream>>>(Abuf, Bbuf, bt_hi, bt_lo,
                                           mb1, mb2, mb3, mb4, mw5, mb5, out);
}

// Round 9
// 385.368 us; speedup vs baseline: 1.0173x; 1.0173x over previous
//
#include <hip/hip_runtime.h>
#include <hip/hip_bf16.h>

#define NQ 20
#define NLAY 51            // N_LAYER+1
#define FEAT 128
#define BATCH 128
#define NN (BATCH * NQ * NLAY)   // 130560
#define NE 524288
#define NPAIR (BATCH * NQ * NQ)  // 51200
#define NB (NN / 256)            // 510
#define EB (NE / 256)            // 2048
#define VOCAB 1021

typedef _Float16 half8 __attribute__((ext_vector_type(8)));
typedef float floatx4 __attribute__((ext_vector_type(4)));
typedef unsigned int uint;

__device__ __forceinline__ float lrelu(float v) { return v >= 0.f ? v : 0.01f * v; }

// pack fp32 -> {fp16 hi (low16), fp16 lo (high16)}
__device__ __forceinline__ uint packhl(float v) {
    _Float16 h = (_Float16)v;
    _Float16 l = (_Float16)(v - (float)h);
    union { _Float16 f; unsigned short u; } hb, lb;
    hb.f = h; lb.f = l;
    return (uint)hb.u | ((uint)lb.u << 16);
}

// unpack 8 packed elems (2x uint4) into hi/lo half8 fragments via v_perm
__device__ __forceinline__ void unpack8(uint4 a, uint4 b, half8& hi, half8& lo) {
    union { uint u[4]; half8 h; } H, L;
    H.u[0] = __builtin_amdgcn_perm(a.y, a.x, 0x05040100u);
    H.u[1] = __builtin_amdgcn_perm(a.w, a.z, 0x05040100u);
    H.u[2] = __builtin_amdgcn_perm(b.y, b.x, 0x05040100u);
    H.u[3] = __builtin_amdgcn_perm(b.w, b.z, 0x05040100u);
    L.u[0] = __builtin_amdgcn_perm(a.y, a.x, 0x07060302u);
    L.u[1] = __builtin_amdgcn_perm(a.w, a.z, 0x07060302u);
    L.u[2] = __builtin_amdgcn_perm(b.y, b.x, 0x07060302u);
    L.u[3] = __builtin_amdgcn_perm(b.w, b.z, 0x07060302u);
    hi = H.h;
    lo = L.h;
}

// ---------------- CSR build ----------------
// count + per-edge ordinal (removes the atomic from k_fill)
__global__ void k_count(const int* __restrict__ dst, int* __restrict__ cnt,
                        int* __restrict__ ord) {
    int e = blockIdx.x * 256 + threadIdx.x;
    ord[e] = atomicAdd(&cnt[dst[e]], 1);
}

// offsets via block-scan + global cursor; meta, S0 seed, idmap.
__global__ void k_offsets(const int* __restrict__ cnt, const int* __restrict__ x,
                          int4* __restrict__ meta, int* __restrict__ cursor,
                          int* __restrict__ flag1, int* __restrict__ idmap) {
    __shared__ int sm[256];
    __shared__ int sbase;
    int t = threadIdx.x, g = blockIdx.x * 256 + t;
    int v = cnt[g];
    sm[t] = v;
    __syncthreads();
    for (int s = 1; s < 256; s <<= 1) {
        int add = (t >= s) ? sm[t - s] : 0;
        __syncthreads();
        sm[t] += add;
        __syncthreads();
    }
    if (t == 255) sbase = atomicAdd(cursor, sm[255]);
    __syncthreads();
    int off = sbase + sm[t] - v;
    float di = rsqrtf((float)(v + 1));  // +1 self loop
    meta[g] = make_int4(off, v, __float_as_int(di), x[g]);
    if (g % (NQ * NLAY) < NQ) flag1[g] = 1;      // S0 seed
    if (g < 1024) idmap[g] = min(g, VOCAB - 1);
}

// fill packed edges {src, norm_bits} and token edges {x[src], norm_bits};
// pos from precomputed ordinal; dinv/off/x from L2-resident meta (2 random reads,
// no atomic). norm = dinv[src]*dinv[dst]. Also mark flag1[src] for S0 dsts.
__global__ void k_fill(const int* __restrict__ src, const int* __restrict__ dst,
                       const int* __restrict__ ord, const int4* __restrict__ meta,
                       int2* __restrict__ csre, int2* __restrict__ csre0,
                       int* __restrict__ flag1) {
    int e = blockIdx.x * 256 + threadIdx.x;
    int d = dst[e];
    int s = src[e];
    int4 md = meta[d];   // {off, deg, dinv_d, x_d}
    int4 ms = meta[s];   // {off, deg, dinv_s, x_s}
    int pos = md.x + ord[e];
    int wb = __float_as_int(__int_as_float(ms.z) * __int_as_float(md.z));
    csre[pos] = make_int2(s, wb);
    csre0[pos] = make_int2(ms.w, wb);
    if (d % (NQ * NLAY) < NQ) flag1[s] = 1;      // src feeds an S0 node
}

// cone pass: blocks [0,NB) emit packed 64B agg-records from flagI (cursor-packed
// dense prefix) + self-mark flagO; blocks [NB, NB+EB) (when flagO) do edge-parallel
// neighbor marking: flagO[src] = 1 for edges whose dst is a flagI member; trailing
// blocks (when rec0q) build the dense-S0 rec0 table.
// Record layout (4 x int4): [0] = {node+1, deg, dinv^2, csr_off}
//                           [1..3] = 6 inline edges {src, norm_bits} (zero-padded)
__global__ void k_s1pass(const int* __restrict__ flagI, const int4* __restrict__ meta,
                         const int2* __restrict__ csre,
                         const int* __restrict__ src, const int* __restrict__ dst,
                         int* __restrict__ cur, int4* __restrict__ recO,
                         int* __restrict__ flagO, int4* __restrict__ rec0q) {
    if (blockIdx.x >= NB) {
        int xb = blockIdx.x - NB;
        if (flagO != nullptr && xb < EB) {
            int e = xb * 256 + threadIdx.x;
            if (flagI[dst[e]]) flagO[src[e]] = 1;   // benign races
            return;
        }
        if (rec0q != nullptr) {
            int rb = xb - (flagO ? EB : 0);
            int q = rb * 256 + threadIdx.x;
            if (q < BATCH * NQ) {
                int b = q / NQ, i = q - b * NQ;
                int node = b * (NQ * NLAY) + i;
                int4 m = meta[node];
                float di = __int_as_float(m.z);
                int dc = min(m.y, 6);
                int2 eb[6];
#pragma unroll
                for (int j = 0; j < 6; j++) eb[j] = (j < dc) ? csre[m.x + j] : make_int2(0, 0);
                int4* r = rec0q + (size_t)q * 4;
                r[0] = make_int4(node + 1, m.y, __float_as_int(di * di), m.x);
                r[1] = make_int4(eb[0].x, eb[0].y, eb[1].x, eb[1].y);
                r[2] = make_int4(eb[2].x, eb[2].y, eb[3].x, eb[3].y);
                r[3] = make_int4(eb[4].x, eb[4].y, eb[5].x, eb[5].y);
            }
        }
        return;
    }
    __shared__ int sm[256];
    __shared__ int sbase;
    int t = threadIdx.x, g = blockIdx.x * 256 + t;
    int v = flagI[g];
    sm[t] = v;
    __syncthreads();
    for (int s = 1; s < 256; s <<= 1) {
        int add = (t >= s) ? sm[t - s] : 0;
        __syncthreads();
        sm[t] += add;
        __syncthreads();
    }
    if (t == 255) sbase = atomicAdd(cur, sm[255]);
    __syncthreads();
    if (v) {
        int slot = sbase + sm[t] - 1;
        int4 m = meta[g];
        float di = __int_as_float(m.z);
        int dc = min(m.y, 6);
        int2 eb[6];
#pragma unroll
        for (int j = 0; j < 6; j++) eb[j] = (j < dc) ? csre[m.x + j] : make_int2(0, 0);
        int4* r = recO + (size_t)slot * 4;
        r[0] = make_int4(g + 1, m.y, __float_as_int(di * di), m.x);
        r[1] = make_int4(eb[0].x, eb[0].y, eb[1].x, eb[1].y);
        r[2] = make_int4(eb[2].x, eb[2].y, eb[3].x, eb[3].y);
        r[3] = make_int4(eb[4].x, eb[4].y, eb[5].x, eb[5].y);
        if (flagO) flagO[g] = 1;   // neighbor marking handled edge-parallel above
    }
}

// ---------------- weight transpose + fp16 hi/lo split, PACKED MFMA-fragment layout -------
#define OFF_GCN 0                 // 5 x K=128 N=128
#define OFF_P0  81920             // combined mw0: K=128 N=512
#define OFF_M1  147456            // mw1: K=256 N=128
#define OFF_M2  180224            // mw2: K=128 N=128
#define OFF_M3  196608            // mw3: K=128 N=64
#define OFF_M4  204800            // mw4: K=64  N=64
#define TS_TOTAL 208896

__global__ void k_tsplit_all(const float* __restrict__ gw, const float* __restrict__ mw0,
                             const float* __restrict__ mw1, const float* __restrict__ mw2,
                             const float* __restrict__ mw3, const float* __restrict__ mw4,
                             _Float16* __restrict__ hi, _Float16* __restrict__ lo) {
    int idx = blockIdx.x * 256 + threadIdx.x;
    const float* src;
    int K, N, rel;
    bool p0 = false;
    if (idx < OFF_P0) {
        int L = (idx - OFF_GCN) >> 14; rel = (idx - OFF_GCN) & 16383;
        src = gw + L * 16384; K = 128; N = 128;
    } else if (idx < OFF_M1) {
        rel = idx - OFF_P0; src = mw0; K = 128; N = 512; p0 = true;
    } else if (idx < OFF_M2) {
        rel = idx - OFF_M1;  src = mw1; K = 256; N = 128;
    } else if (idx < OFF_M3) {
        rel = idx - OFF_M2;  src = mw2; K = 128; N = 128;
    } else if (idx < OFF_M4) {
        rel = idx - OFF_M3;  src = mw3; K = 128; N = 64;
    } else {
        rel = idx - OFF_M4;  src = mw4; K = 64;  N = 64;
    }
    int kblks = K >> 5;
    int j = rel & 7;
    int lane = (rel >> 3) & 63;
    int t2 = rel >> 9;
    int kblk = t2 % kblks;
    int ntile = t2 / kblks;
    int col = ntile * 16 + (lane & 15);
    int k = kblk * 32 + ((lane >> 4) << 3) + j;
    float f;
    if (p0) {
        f = (col < 256) ? src[k * 256 + col] : src[(k + 128) * 256 + (col - 256)];
    } else {
        f = src[k * N + col];
    }
    _Float16 h = (_Float16)f;
    hi[idx] = h;
    lo[idx] = (_Float16)(f - (float)h);
}

// ---------------- split-fp16 MFMA GEMM (layer-0 token table only) ----------------
template <int NT_N, bool LEAKY, bool BIAS, bool P0SPLIT, bool FUSEA, bool GATHA, bool LISTM>
__launch_bounds__(256, 2)
__global__ void hgemm(const float* __restrict__ A,
                      const float* __restrict__ FA, const float* __restrict__ FB,
                      const _Float16* __restrict__ Bh, const _Float16* __restrict__ Bl,
                      const float* __restrict__ bias,
                      float* __restrict__ C, float* __restrict__ C2,
                      int N, int K, const int* __restrict__ gmap,
                      const int* __restrict__ listm) {
    if (LISTM) {
        if ((unsigned)listm[blockIdx.x * 128] >= (unsigned)NN) return;  // all-sentinel block
    }
    const int KB = K >> 5;
    const int lane = threadIdx.x & 63;
    const int wid = threadIdx.x >> 6;
    const int lm = lane & 15, lq = lane >> 4;
    const int m0 = blockIdx.x * 128 + wid * 32;
    const int n0t = blockIdx.y * NT_N;

    const float* arow[2];
    const float* brow[2];
#pragma unroll
    for (int mt = 0; mt < 2; mt++) {
        int row = m0 + mt * 16 + lm;
        if (FUSEA) {
            int b = row / (NQ * NQ);
            int rr = row - b * (NQ * NQ);
            int i = rr / NQ;
            int j = rr - i * NQ;
            arow[mt] = FA + (size_t)(b * NQ + i) * 256;
            brow[mt] = FB + (size_t)(b * NQ + j) * 256;
        } else if (GATHA) {
            arow[mt] = A + (size_t)gmap[row] * K;
        } else if (LISTM) {
            int lr = listm[row];
            lr = ((unsigned)lr < (unsigned)NN) ? lr : 0;
            arow[mt] = A + (size_t)lr * K;
        } else {
            arow[mt] = A + (size_t)row * K;
        }
    }

    floatx4 acc[2][NT_N];
#pragma unroll
    for (int mt = 0; mt < 2; mt++)
#pragma unroll
        for (int nt = 0; nt < NT_N; nt++) acc[mt][nt] = (floatx4)0.f;

    for (int kb = 0; kb < KB; kb++) {
        const int k0 = kb * 32 + lq * 8;
        half8 ahi[2], alo[2];
#pragma unroll
        for (int mt = 0; mt < 2; mt++) {
            floatx4 av0, av1;
            if (FUSEA) {
                floatx4 fa0 = *(const floatx4*)(arow[mt] + k0);
                floatx4 fa1 = *(const floatx4*)(arow[mt] + k0 + 4);
                floatx4 fb0 = *(const floatx4*)(brow[mt] + k0);
                floatx4 fb1 = *(const floatx4*)(brow[mt] + k0 + 4);
#pragma unroll
                for (int q = 0; q < 4; q++) {
                    av0[q] = lrelu(fa0[q] + fb0[q]);
                    av1[q] = lrelu(fa1[q] + fb1[q]);
                }
            } else {
                av0 = *(const floatx4*)(arow[mt] + k0);
                av1 = *(const floatx4*)(arow[mt] + k0 + 4);
            }
#pragma unroll
            for (int q = 0; q < 4; q++) {
                _Float16 h0 = (_Float16)av0[q];
                ahi[mt][q] = h0;
                alo[mt][q] = (_Float16)(av0[q] - (float)h0);
                _Float16 h1 = (_Float16)av1[q];
                ahi[mt][4 + q] = h1;
                alo[mt][4 + q] = (_Float16)(av1[q] - (float)h1);
            }
        }
#pragma unroll
        for (int nt = 0; nt < NT_N; nt++) {
            size_t boff = (((size_t)(n0t + nt) * KB + kb) * 64 + lane) * 8;
            half8 bhi = *(const half8*)(Bh + boff);
            half8 blo = *(const half8*)(Bl + boff);
#pragma unroll
            for (int mt = 0; mt < 2; mt++) {
                acc[mt][nt] = __builtin_amdgcn_mfma_f32_16x16x32_f16(ahi[mt], bhi, acc[mt][nt], 0, 0, 0);
                acc[mt][nt] = __builtin_amdgcn_mfma_f32_16x16x32_f16(ahi[mt], blo, acc[mt][nt], 0, 0, 0);
                acc[mt][nt] = __builtin_amdgcn_mfma_f32_16x16x32_f16(alo[mt], bhi, acc[mt][nt], 0, 0, 0);
            }
        }
    }

    // store-row mapping (C/D layout: col=lane&15, row=(lane>>4)*4+reg)
    int strow[2][4];
    bool svalid[2][4];
#pragma unroll
    for (int mt = 0; mt < 2; mt++)
#pragma unroll
        for (int r = 0; r < 4; r++) {
            int mlog = m0 + mt * 16 + lq * 4 + r;
            if (LISTM) {
                int sr = listm[mlog];
                svalid[mt][r] = (unsigned)sr < (unsigned)NN;
                strow[mt][r] = svalid[mt][r] ? sr : 0;
            } else {
                svalid[mt][r] = true;
                strow[mt][r] = mlog;
            }
        }

#pragma unroll
    for (int nt = 0; nt < NT_N; nt++) {
        int col = (n0t + nt) * 16 + lm;
        float bv = (BIAS || P0SPLIT) ? bias[col < 256 ? col : 0] : 0.f;
#pragma unroll
        for (int mt = 0; mt < 2; mt++) {
#pragma unroll
            for (int r = 0; r < 4; r++) {
                if (!svalid[mt][r]) continue;
                int row = strow[mt][r];
                float val = acc[mt][nt][r];
                if (P0SPLIT) {
                    if (col < 256) C[(size_t)row * 256 + col] = val + bv;
                    else C2[(size_t)row * 256 + col - 256] = val;
                } else {
                    if (BIAS) val += bv;
                    if (LEAKY) val = lrelu(val);
                    C[(size_t)row * N + col] = val;
                }
            }
        }
    }
}

// ---------------- FUSED GCN layer: aggregate-then-GEMM (A·h)·W ----------------
// 16-slot blocks: phase A is a SINGLE pass (8 groups x 2 slots), writing packed
// hi/lo rows into LDS X, raw residual rows into LDS R, node ids into NID.
// Phase B: 4 waves compute the same 16 rows over disjoint 32-col slices
// (nt = wid*2+{0,1}), K=128; bias + (leaky) + residual from R.
// FINAL: instead of storing hq to global, repack rows into X and run phase C —
// the combined-mw0 P0 GEMM (K=128, N=512) writing Abuf (+mb0) / Bbuf directly.
template <bool LEAKY, bool FINAL>
__launch_bounds__(256, 8)
__global__ void k_lagg(const float* __restrict__ in, float* __restrict__ outp,
                       const int4* __restrict__ rec, const int2* __restrict__ csre,
                       const int* __restrict__ cntp, int fixcnt,
                       const _Float16* __restrict__ Bh, const _Float16* __restrict__ Bl,
                       const float* __restrict__ bias,
                       const _Float16* __restrict__ BhP, const _Float16* __restrict__ BlP,
                       const float* __restrict__ mb0p,
                       float* __restrict__ Abuf, float* __restrict__ Bbuf) {
    int lcnt = cntp ? *cntp : fixcnt;
    int sbase = blockIdx.x * 16;
    if (sbase >= lcnt) return;
    __shared__ uint X[16][132];
    __shared__ float R[16][132];
    __shared__ int NID[16];
    int tid = threadIdx.x;
    int sl = tid & 31;
    int grp = tid >> 5;
    const float4* in4 = (const float4*)in;
    // ---- phase A: aggregate 16 rows, one pass (8 groups x 2 slots) ----
    {
        int lrow0 = grp * 2;
        int p0i = sbase + lrow0, p1i = p0i + 1;
        bool val0 = p0i < lcnt, val1 = p1i < lcnt;
        const int4* r0p = rec + (size_t)(val0 ? p0i : 0) * 4;
        const int4* r1p = rec + (size_t)(val1 ? p1i : 0) * 4;
        int4 hd0 = r0p[0], ea0 = r0p[1], eb0 = r0p[2], ec0 = r0p[3];
        int4 hd1 = r1p[0], ea1 = r1p[1], eb1 = r1p[2], ec1 = r1p[3];
        int n0 = hd0.x - 1;
        int n1 = hd1.x - 1;
        if (sl == 0) {
            NID[lrow0] = n0;
            NID[lrow0 + 1] = n1;
        }
        float s20 = __int_as_float(hd0.z), s21 = __int_as_float(hd1.z);
        float4 v0  = in4[(size_t)n0 * 32 + sl];
        float4 v1  = in4[(size_t)n1 * 32 + sl];
        float4 u00 = in4[(size_t)ea0.x * 32 + sl];
        float4 u01 = in4[(size_t)ea0.z * 32 + sl];
        float4 u02 = in4[(size_t)eb0.x * 32 + sl];
        float4 u03 = in4[(size_t)eb0.z * 32 + sl];
        float4 u04 = in4[(size_t)ec0.x * 32 + sl];
        float4 u05 = in4[(size_t)ec0.z * 32 + sl];
        float4 u10 = in4[(size_t)ea1.x * 32 + sl];
        float4 u11 = in4[(size_t)ea1.z * 32 + sl];
        float4 u12 = in4[(size_t)eb1.x * 32 + sl];
        float4 u13 = in4[(size_t)eb1.z * 32 + sl];
        float4 u14 = in4[(size_t)ec1.x * 32 + sl];
        float4 u15 = in4[(size_t)ec1.z * 32 + sl];
        // stash raw residual rows for phase B
        *(float4*)&R[lrow0][sl * 4] = v0;
        *(float4*)&R[lrow0 + 1][sl * 4] = v1;
        float w00 = __int_as_float(ea0.y), w01 = __int_as_float(ea0.w);
        float w02 = __int_as_float(eb0.y), w03 = __int_as_float(eb0.w);
        float w04 = __int_as_float(ec0.y), w05 = __int_as_float(ec0.w);
        float w10 = __int_as_float(ea1.y), w11 = __int_as_float(ea1.w);
        float w12 = __int_as_float(eb1.y), w13 = __int_as_float(eb1.w);
        float w14 = __int_as_float(ec1.y), w15 = __int_as_float(ec1.w);
        float a0x = v0.x * s20 + u00.x * w00 + u01.x * w01 + u02.x * w02 + u03.x * w03 + u04.x * w04 + u05.x * w05;
        float a0y = v0.y * s20 + u00.y * w00 + u01.y * w01 + u02.y * w02 + u03.y * w03 + u04.y * w04 + u05.y * w05;
        float a0z = v0.z * s20 + u00.z * w00 + u01.z * w01 + u02.z * w02 + u03.z * w03 + u04.z * w04 + u05.z * w05;
        float a0w = v0.w * s20 + u00.w * w00 + u01.w * w01 + u02.w * w02 + u03.w * w03 + u04.w * w04 + u05.w * w05;
        float a1x = v1.x * s21 + u10.x * w10 + u11.x * w11 + u12.x * w12 + u13.x * w13 + u14.x * w14 + u15.x * w15;
        float a1y = v1.y * s21 + u10.y * w10 + u11.y * w11 + u12.y * w12 + u13.y * w13 + u14.y * w14 + u15.y * w15;
        float a1z = v1.z * s21 + u10.z * w10 + u11.z * w11 + u12.z * w12 + u13.z * w13 + u14.z * w14 + u15.z * w15;
        float a1w = v1.w * s21 + u10.w * w10 + u11.w * w11 + u12.w * w12 + u13.w * w13 + u14.w * w14 + u15.w * w15;
        int deg0 = val0 ? hd0.y : 0, deg1 = val1 ? hd1.y : 0;
        int dm = max(deg0, deg1);
        if (dm > 6) {
            // rare overflow path: clamped CSR loop for edges >= 6
            int off0 = hd0.w, off1 = hd1.w;
            int d0c = max(deg0 - 1, 0), d1c = max(deg1 - 1, 0);
            for (int e = 6; e < dm; e += 6) {
                int2 e00 = csre[off0 + min(e,     d0c)];
                int2 e01 = csre[off0 + min(e + 1, d0c)];
                int2 e02 = csre[off0 + min(e + 2, d0c)];
                int2 e03 = csre[off0 + min(e + 3, d0c)];
                int2 e04 = csre[off0 + min(e + 4, d0c)];
                int2 e05 = csre[off0 + min(e + 5, d0c)];
                int2 e10 = csre[off1 + min(e,     d1c)];
                int2 e11 = csre[off1 + min(e + 1, d1c)];
                int2 e12 = csre[off1 + min(e + 2, d1c)];
                int2 e13 = csre[off1 + min(e + 3, d1c)];
                int2 e14 = csre[off1 + min(e + 4, d1c)];
                int2 e15 = csre[off1 + min(e + 5, d1c)];
                float4 x00 = in4[(size_t)e00.x * 32 + sl];
                float4 x01 = in4[(size_t)e01.x * 32 + sl];
                float4 x02 = in4[(size_t)e02.x * 32 + sl];
                float4 x03 = in4[(size_t)e03.x * 32 + sl];
                float4 x04 = in4[(size_t)e04.x * 32 + sl];
                float4 x05 = in4[(size_t)e05.x * 32 + sl];
                float4 x10 = in4[(size_t)e10.x * 32 + sl];
                float4 x11 = in4[(size_t)e11.x * 32 + sl];
                float4 x12 = in4[(size_t)e12.x * 32 + sl];
                float4 x13 = in4[(size_t)e13.x * 32 + sl];
                float4 x14 = in4[(size_t)e14.x * 32 + sl];
                float4 x15 = in4[(size_t)e15.x * 32 + sl];
                float q00 = (e     < deg0) ? __int_as_float(e00.y) : 0.f;
                float q01 = (e + 1 < deg0) ? __int_as_float(e01.y) : 0.f;
                float q02 = (e + 2 < deg0) ? __int_as_float(e02.y) : 0.f;
                float q03 = (e + 3 < deg0) ? __int_as_float(e03.y) : 0.f;
                float q04 = (e + 4 < deg0) ? __int_as_float(e04.y) : 0.f;
                float q05 = (e + 5 < deg0) ? __int_as_float(e05.y) : 0.f;
                float q10 = (e     < deg1) ? __int_as_float(e10.y) : 0.f;
                float q11 = (e + 1 < deg1) ? __int_as_float(e11.y) : 0.f;
                float q12 = (e + 2 < deg1) ? __int_as_float(e12.y) : 0.f;
                float q13 = (e + 3 < deg1) ? __int_as_float(e13.y) : 0.f;
                float q14 = (e + 4 < deg1) ? __int_as_float(e14.y) : 0.f;
                float q15 = (e + 5 < deg1) ? __int_as_float(e15.y) : 0.f;
                a0x += x00.x * q00 + x01.x * q01 + x02.x * q02 + x03.x * q03 + x04.x * q04 + x05.x * q05;
                a0y += x00.y * q00 + x01.y * q01 + x02.y * q02 + x03.y * q03 + x04.y * q04 + x05.y * q05;
                a0z += x00.z * q00 + x01.z * q01 + x02.z * q02 + x03.z * q03 + x04.z * q04 + x05.z * q05;
                a0w += x00.w * q00 + x01.w * q01 + x02.w * q02 + x03.w * q03 + x04.w * q04 + x05.w * q05;
                a1x += x10.x * q10 + x11.x * q11 + x12.x * q12 + x13.x * q13 + x14.x * q14 + x15.x * q15;
                a1y += x10.y * q10 + x11.y * q11 + x12.y * q12 + x13.y * q13 + x14.y * q14 + x15.y * q15;
                a1z += x10.z * q10 + x11.z * q11 + x12.z * q12 + x13.z * q13 + x14.z * q14 + x15.z * q15;
                a1w += x10.w * q10 + x11.w * q11 + x12.w * q12 + x13.w * q13 + x14.w * q14 + x15.w * q15;
            }
        }
        *(uint4*)&X[lrow0][sl * 4] =
            make_uint4(packhl(a0x), packhl(a0y), packhl(a0z), packhl(a0w));
        *(uint4*)&X[lrow0 + 1][sl * 4] =
            make_uint4(packhl(a1x), packhl(a1y), packhl(a1z), packhl(a1w));
    }
    __syncthreads();
    // ---- phase B: 4 waves, same 16 rows, disjoint 32-col slices; K=128 ----
    const int lane = tid & 63;
    const int wid = tid >> 6;
    const int lm = lane & 15, lq = lane >> 4;
    floatx4 acc[2];
    acc[0] = (floatx4)0.f;
    acc[1] = (floatx4)0.f;
#pragma unroll
    for (int kb = 0; kb < 4; kb++) {
        const int k0 = kb * 32 + lq * 8;
        uint4 pa = *(const uint4*)&X[lm][k0];
        uint4 pb = *(const uint4*)&X[lm][k0 + 4];
        half8 ahi, alo;
        unpack8(pa, pb, ahi, alo);
#pragma unroll
        for (int ntl = 0; ntl < 2; ntl++) {
            int nt = wid * 2 + ntl;
            size_t boff = (((size_t)nt * 4 + kb) * 64 + lane) * 8;
            half8 bhi = *(const half8*)(Bh + boff);
            half8 blo = *(const half8*)(Bl + boff);
            acc[ntl] = __builtin_amdgcn_mfma_f32_16x16x32_f16(ahi, bhi, acc[ntl], 0, 0, 0);
            acc[ntl] = __builtin_amdgcn_mfma_f32_16x16x32_f16(ahi, blo, acc[ntl], 0, 0, 0);
            acc[ntl] = __builtin_amdgcn_mfma_f32_16x16x32_f16(alo, bhi, acc[ntl], 0, 0, 0);
        }
    }
    if (FINAL) __syncthreads();   // all phase-B X reads done before X overwrite
    // ---- C-write: bias + (leaky) + residual from R ----
    int nodes[4];
    bool sval[4];
#pragma unroll
    for (int r = 0; r < 4; r++) {
        int slot = sbase + lq * 4 + r;
        sval[r] = slot < lcnt;
        nodes[r] = NID[lq * 4 + r];
    }
#pragma unroll
    for (int ntl = 0; ntl < 2; ntl++) {
        int col = (wid * 2 + ntl) * 16 + lm;
        float bv = bias[col];
#pragma unroll
        for (int r = 0; r < 4; r++) {
            if (!sval[r]) continue;
            float val = acc[ntl][r] + bv;
            if (LEAKY) val = lrelu(val);
            val += R[lq * 4 + r][col];
            if (FINAL)
                X[lq * 4 + r][col] = packhl(val);   // hq row stays in LDS
            else
                outp[(size_t)nodes[r] * FEAT + col] = val;
        }
    }
    // ---- phase C (FINAL only): P0 GEMM, K=128 N=512, write Abuf/Bbuf ----
    if (FINAL) {
        __syncthreads();
#pragma unroll
        for (int c = 0; c < 2; c++) {
            floatx4 acc4[4];
#pragma unroll
            for (int nt = 0; nt < 4; nt++) acc4[nt] = (floatx4)0.f;
#pragma unroll
            for (int kb = 0; kb < 4; kb++) {
                const int k0 = kb * 32 + lq * 8;
                uint4 pa = *(const uint4*)&X[lm][k0];
                uint4 pb = *(const uint4*)&X[lm][k0 + 4];
                half8 ahi, alo;
                unpack8(pa, pb, ahi, alo);
#pragma unroll
                for (int nt = 0; nt < 4; nt++) {
                    int T = wid * 8 + c * 4 + nt;
                    size_t boff = (((size_t)T * 4 + kb) * 64 + lane) * 8;
                    half8 bhi = *(const half8*)(BhP + boff);
                    half8 blo = *(const half8*)(BlP + boff);
                    acc4[nt] = __builtin_amdgcn_mfma_f32_16x16x32_f16(ahi, bhi, acc4[nt], 0, 0, 0);
                    acc4[nt] = __builtin_amdgcn_mfma_f32_16x16x32_f16(ahi, blo, acc4[nt], 0, 0, 0);
                    acc4[nt] = __builtin_amdgcn_mfma_f32_16x16x32_f16(alo, bhi, acc4[nt], 0, 0, 0);
                }
            }
#pragma unroll
            for (int nt = 0; nt < 4; nt++) {
                int T = wid * 8 + c * 4 + nt;
                int col = T * 16 + lm;
#pragma unroll
                for (int r = 0; r < 4; r++) {
                    int q = sbase + lq * 4 + r;
                    float val = acc4[nt][r];
                    if (col < 256) Abuf[(size_t)q * 256 + col] = val + mb0p[col];
                    else Bbuf[(size_t)q * 256 + col - 256] = val;
                }
            }
        }
    }
}

// ---------------- fused pair MLP: wave-local in-place LDS, no barriers ----------------
template <int KB, int NT>
__device__ __forceinline__ void pair_stage(uint (*__restrict__ X)[132],
                                           const _Float16* __restrict__ Bh,
                                           const _Float16* __restrict__ Bl,
                                           const float* __restrict__ bias,
                                           int srow, int lane) {
    const int lm = lane & 15, lq = lane >> 4;
    floatx4 acc[NT];
#pragma unroll
    for (int nt = 0; nt < NT; nt++) acc[nt] = (floatx4)0.f;
#pragma unroll
    for (int kb = 0; kb < KB; kb++) {
        const int k0 = kb * 32 + lq * 8;
        uint4 pa = *(const uint4*)&X[srow + lm][k0];
        uint4 pb = *(const uint4*)&X[srow + lm][k0 + 4];
        half8 ahi, alo;
        unpack8(pa, pb, ahi, alo);
#pragma unroll
        for (int nt = 0; nt < NT; nt++) {
            size_t boff = (((size_t)nt * KB + kb) * 64 + lane) * 8;
            half8 bhi = *(const half8*)(Bh + boff);
            half8 blo = *(const half8*)(Bl + boff);
            acc[nt] = __builtin_amdgcn_mfma_f32_16x16x32_f16(ahi, bhi, acc[nt], 0, 0, 0);
            acc[nt] = __builtin_amdgcn_mfma_f32_16x16x32_f16(ahi, blo, acc[nt], 0, 0, 0);
            acc[nt] = __builtin_amdgcn_mfma_f32_16x16x32_f16(alo, bhi, acc[nt], 0, 0, 0);
        }
    }
#pragma unroll
    for (int nt = 0; nt < NT; nt++) {
        int col = nt * 16 + lm;
        float bv = bias[col];
#pragma unroll
        for (int r = 0; r < 4; r++) {
            X[srow + lq * 4 + r][col] = packhl(lrelu(acc[nt][r] + bv));
        }
    }
}

__launch_bounds__(256, 4)
__global__ void k_pair(const float* __restrict__ FA, const float* __restrict__ FB,
                       const _Float16* __restrict__ bth, const _Float16* __restrict__ btl,
                       const float* __restrict__ mb1, const float* __restrict__ mb2,
                       const float* __restrict__ mb3, const float* __restrict__ mb4,
                       const float* __restrict__ mw5, const float* __restrict__ mb5,
                       float* __restrict__ out) {
    __shared__ uint X[64][132];
    const int lane = threadIdx.x & 63;
    const int wid = threadIdx.x >> 6;
    const int lm = lane & 15, lq = lane >> 4;
    const int srow = wid * 16;
    const int rbase = blockIdx.x * 64;

    // ---- stage 1 (M1): K=256 via fused concat(h_i,h_j)+lrelu, N=128 -> X ----
    {
        const int grow = rbase + srow + lm;
        int b = grow / (NQ * NQ);
        int rr = grow - b * (NQ * NQ);
        int i = rr / NQ;
        int j = rr - i * NQ;
        const float* arow = FA + (size_t)(b * NQ + i) * 256;
        const float* brow = FB + (size_t)(b * NQ + j) * 256;
        const _Float16* Bh = bth + OFF_M1;
        const _Float16* Bl = btl + OFF_M1;
        floatx4 acc[8];
#pragma unroll
        for (int nt = 0; nt < 8; nt++) acc[nt] = (floatx4)0.f;
        const int KB = 8;
#pragma unroll
        for (int kb = 0; kb < KB; kb++) {
            const int k0 = kb * 32 + lq * 8;
            floatx4 fa0 = *(const floatx4*)(arow + k0);
            floatx4 fa1 = *(const floatx4*)(arow + k0 + 4);
            floatx4 fb0 = *(const floatx4*)(brow + k0);
            floatx4 fb1 = *(const floatx4*)(brow + k0 + 4);
            half8 ahi, alo;
#pragma unroll
            for (int q = 0; q < 4; q++) {
                float v0 = lrelu(fa0[q] + fb0[q]);
                float v1 = lrelu(fa1[q] + fb1[q]);
                _Float16 h0 = (_Float16)v0;
                ahi[q] = h0;
                alo[q] = (_Float16)(v0 - (float)h0);
                _Float16 h1 = (_Float16)v1;
                ahi[4 + q] = h1;
                alo[4 + q] = (_Float16)(v1 - (float)h1);
            }
#pragma unroll
            for (int nt = 0; nt < 8; nt++) {
                size_t boff = (((size_t)nt * KB + kb) * 64 + lane) * 8;
                half8 bhi = *(const half8*)(Bh + boff);
                half8 blo = *(const half8*)(Bl + boff);
                acc[nt] = __builtin_amdgcn_mfma_f32_16x16x32_f16(ahi, bhi, acc[nt], 0, 0, 0);
                acc[nt] = __builtin_amdgcn_mfma_f32_16x16x32_f16(ahi, blo, acc[nt], 0, 0, 0);
                acc[nt] = __builtin_amdgcn_mfma_f32_16x16x32_f16(alo, bhi, acc[nt], 0, 0, 0);
            }
        }
#pragma unroll
        for (int nt = 0; nt < 8; nt++) {
            int col = nt * 16 + lm;
            float bv = mb1[col];
#pragma unroll
            for (int r = 0; r < 4; r++) {
                X[srow + lq * 4 + r][col] = packhl(lrelu(acc[nt][r] + bv));
            }
        }
    }
    // ---- stage 2 (M2): K=128 N=128, in place ----
    pair_stage<4, 8>(X, bth + OFF_M2, btl + OFF_M2, mb2, srow, lane);
    // ---- stage 3 (M3): K=128 N=64, in place ----
    pair_stage<4, 4>(X, bth + OFF_M3, btl + OFF_M3, mb3, srow, lane);
    // ---- stage 4 (M4): K=64 N=64, in place ----
    pair_stage<2, 4>(X, bth + OFF_M4, btl + OFF_M4, mb4, srow, lane);
    // ---- stage 5 (M5): dot-64 per row + atomic symmetrize into out ----
    {
        int row = srow + (lane >> 2);
        int part = lane & 3;
        float s = 0.f;
#pragma unroll
        for (int c4 = 0; c4 < 4; c4++) {
            int c0 = part * 16 + c4 * 4;
            uint4 u = *(const uint4*)&X[row][c0];
            const float* wp = mw5 + c0;
            uint uu[4] = {u.x, u.y, u.z, u.w};
#pragma unroll
            for (int q = 0; q < 4; q++) {
                union { unsigned short us; _Float16 f; } ch, cl;
                ch.us = (unsigned short)(uu[q] & 0xffffu);
                cl.us = (unsigned short)(uu[q] >> 16);
                s += ((float)ch.f + (float)cl.f) * wp[q];
            }
        }
        s += __shfl_xor(s, 1);
        s += __shfl_xor(s, 2);
        if (part == 0) {
            int p = rbase + row;
            int b = p / (NQ * NQ);
            int rr = p - b * (NQ * NQ);
            int i = rr / NQ, j = rr - i * NQ;
            float hv = 0.5f * (s + mb5[0]);
            atomicAdd(&out[(size_t)b * NQ * NQ + i * NQ + j], hv);
            atomicAdd(&out[(size_t)b * NQ * NQ + j * NQ + i], hv);
        }
    }
}

// ---------------- layer-0 aggregation from the L2-resident token table ----------------
__global__ void k_agg0(const float* __restrict__ embW, const float* __restrict__ emb,
                       float* __restrict__ h,
                       const int4* __restrict__ meta, const int2* __restrict__ csre0,
                       const float* __restrict__ bias) {
    int tid = threadIdx.x;
    int sl = tid & 31;
    int p = blockIdx.x * 8 + (tid >> 5);
    int n0 = p * 2, n1 = n0 + 1;
    int4 m0 = meta[n0], m1 = meta[n1];
    float di0 = __int_as_float(m0.z), di1 = __int_as_float(m1.z);
    int off0 = m0.x, deg0 = m0.y;
    int off1 = m1.x, deg1 = m1.y;
    float4 v0 = ((const float4*)(embW + (size_t)m0.w * FEAT))[sl];
    float4 v1 = ((const float4*)(embW + (size_t)m1.w * FEAT))[sl];
    float4 ho0 = ((const float4*)(emb + (size_t)m0.w * FEAT))[sl];
    float4 ho1 = ((const float4*)(emb + (size_t)m1.w * FEAT))[sl];
    float s20 = di0 * di0, s21 = di1 * di1;
    float a0x = v0.x * s20, a0y = v0.y * s20, a0z = v0.z * s20, a0w = v0.w * s20;
    float a1x = v1.x * s21, a1y = v1.y * s21, a1z = v1.z * s21, a1w = v1.w * s21;
    int d0c = max(deg0 - 1, 0), d1c = max(deg1 - 1, 0);
    int dm = max(deg0, deg1);
    for (int e = 0; e < dm; e += 4) {
        int2 e00 = csre0[off0 + min(e,     d0c)];
        int2 e01 = csre0[off0 + min(e + 1, d0c)];
        int2 e02 = csre0[off0 + min(e + 2, d0c)];
        int2 e03 = csre0[off0 + min(e + 3, d0c)];
        int2 e10 = csre0[off1 + min(e,     d1c)];
        int2 e11 = csre0[off1 + min(e + 1, d1c)];
        int2 e12 = csre0[off1 + min(e + 2, d1c)];
        int2 e13 = csre0[off1 + min(e + 3, d1c)];
        float4 u00 = ((const float4*)(embW + (size_t)e00.x * FEAT))[sl];
        float4 u01 = ((const float4*)(embW + (size_t)e01.x * FEAT))[sl];
        float4 u02 = ((const float4*)(embW + (size_t)e02.x * FEAT))[sl];
        float4 u03 = ((const float4*)(embW + (size_t)e03.x * FEAT))[sl];
        float4 u10 = ((const float4*)(embW + (size_t)e10.x * FEAT))[sl];
        float4 u11 = ((const float4*)(embW + (size_t)e11.x * FEAT))[sl];
        float4 u12 = ((const float4*)(embW + (size_t)e12.x * FEAT))[sl];
        float4 u13 = ((const float4*)(embW + (size_t)e13.x * FEAT))[sl];
        float w00 = (e     < deg0) ? __int_as_float(e00.y) : 0.f;
        float w01 = (e + 1 < deg0) ? __int_as_float(e01.y) : 0.f;
        float w02 = (e + 2 < deg0) ? __int_as_float(e02.y) : 0.f;
        float w03 = (e + 3 < deg0) ? __int_as_float(e03.y) : 0.f;
        float w10 = (e     < deg1) ? __int_as_float(e10.y) : 0.f;
        float w11 = (e + 1 < deg1) ? __int_as_float(e11.y) : 0.f;
        float w12 = (e + 2 < deg1) ? __int_as_float(e12.y) : 0.f;
        float w13 = (e + 3 < deg1) ? __int_as_float(e13.y) : 0.f;
        a0x += u00.x * w00 + u01.x * w01 + u02.x * w02 + u03.x * w03;
        a0y += u00.y * w00 + u01.y * w01 + u02.y * w02 + u03.y * w03;
        a0z += u00.z * w00 + u01.z * w01 + u02.z * w02 + u03.z * w03;
        a0w += u00.w * w00 + u01.w * w01 + u02.w * w02 + u03.w * w03;
        a1x += u10.x * w10 + u11.x * w11 + u12.x * w12 + u13.x * w13;
        a1y += u10.y * w10 + u11.y * w11 + u12.y * w12 + u13.y * w13;
        a1z += u10.z * w10 + u11.z * w11 + u12.z * w12 + u13.z * w13;
        a1w += u10.w * w10 + u11.w * w11 + u12.w * w12 + u13.w * w13;
    }
    float4 bv = ((const float4*)bias)[sl];
    float4 r0, r1;
    r0.x = lrelu(a0x + bv.x) + ho0.x;
    r0.y = lrelu(a0y + bv.y) + ho0.y;
    r0.z = lrelu(a0z + bv.z) + ho0.z;
    r0.w = lrelu(a0w + bv.w) + ho0.w;
    r1.x = lrelu(a1x + bv.x) + ho1.x;
    r1.y = lrelu(a1y + bv.y) + ho1.y;
    r1.z = lrelu(a1z + bv.z) + ho1.z;
    r1.w = lrelu(a1w + bv.w) + ho1.w;
    ((float4*)(h + (size_t)n0 * FEAT))[sl] = r0;
    ((float4*)(h + (size_t)n1 * FEAT))[sl] = r1;
}

extern "C" void kernel_launch(void* const* d_in, const int* in_sizes, int n_in,
                              void* d_out, int out_size, void* d_ws, size_t ws_size,
                              hipStream_t stream) {
    const int* x = (const int*)d_in[0];
    const int* ei = (const int*)d_in[1];
    const int* e_src = ei;
    const int* e_dst = ei + NE;
    const float* emb = (const float*)d_in[2];
    const float* gw = (const float*)d_in[3];   // [5,128,128]
    const float* gb = (const float*)d_in[4];   // [5,128]
    const float* mw0 = (const float*)d_in[5];
    const float* mb0 = (const float*)d_in[6];
    const float* mw1 = (const float*)d_in[7];
    const float* mb1 = (const float*)d_in[8];
    const float* mw2 = (const float*)d_in[9];
    const float* mb2 = (const float*)d_in[10];
    const float* mw3 = (const float*)d_in[11];
    const float* mb3 = (const float*)d_in[12];
    const float* mw4 = (const float*)d_in[13];
    const float* mb4 = (const float*)d_in[14];
    const float* mw5 = (const float*)d_in[15];
    const float* mb5 = (const float*)d_in[16];
    float* out = (float*)d_out;

    float* wsf = (float*)d_ws;
    size_t o = 0;
    const size_t HSZ = (size_t)NN * FEAT;             // 16,711,680
    float* h  = wsf + o; o += HSZ;    // layer ping buffer
    float* hw = wsf + o; o += HSZ;    // layer pong buffer
    // zero-memset region: cnt, fill(unused pad), flag1, flag2, flag3, cursors (contiguous)
    int* cnt   = (int*)(wsf + o); o += NN;
    int* flag1 = (int*)(wsf + o); o += NN;
    int* flag2 = (int*)(wsf + o); o += NN;
    int* flag3 = (int*)(wsf + o); o += NN;
    int* curs  = (int*)(wsf + o); o += 16;   // [0]=offs [1]=S1 [2]=S2 [3]=S3
    int* ord  = (int*)(wsf + o); o += NE;    // per-edge ordinal (no memset)
    int4* meta = (int4*)(wsf + o); o += 4 * (size_t)NN;
    int2* csre  = (int2*)(wsf + o); o += 2 * (size_t)(NE + 8);  // +8 slop for deg-0 clamp
    int2* csre0 = (int2*)(wsf + o); o += 2 * (size_t)(NE + 8);  // token edges
    int* idmap = (int*)(wsf + o); o += 1024;
    float* embW = wsf + o; o += (size_t)1024 * FEAT;          // emb@W0 table
    float* Abuf = wsf + o; o += (size_t)BATCH * NQ * 256;     // 655,360
    float* Bbuf = wsf + o; o += (size_t)BATCH * NQ * 256;     // 655,360
    // packed agg records: 64B per node per list (no memset; validity via cursors)
    int4* rec1 = (int4*)(wsf + o); o += 16 * (size_t)NN;
    int4* rec2 = (int4*)(wsf + o); o += 16 * (size_t)NN;
    int4* rec3 = (int4*)(wsf + o); o += 16 * (size_t)NN;
    int4* rec0 = (int4*)(wsf + o); o += 16 * (size_t)(BATCH * NQ);
    _Float16* bt_hi = (_Float16*)(wsf + o); o += (TS_TOTAL + 2) / 2;
    _Float16* bt_lo = (_Float16*)(wsf + o); o += (TS_TOTAL + 2) / 2;

    // --- zero output (k_pair accumulates symmetrized halves atomically) ---
    hipMemsetAsync(out, 0, (size_t)NPAIR * sizeof(float), stream);

    // --- weight transpose+split+pack ---
    k_tsplit_all<<<TS_TOTAL / 256, 256, 0, stream>>>(gw, mw0, mw1, mw2, mw3, mw4, bt_hi, bt_lo);

    // --- CSR build + cone records S1/S2/S3 + rec0 (folded into first s1pass) ---
    hipMemsetAsync(cnt, 0, (4 * NN + 16) * sizeof(int), stream); // cnt+flags+cursors
    hipMemsetAsync(csre + NE, 0, 8 * sizeof(int2), stream);      // slop
    hipMemsetAsync(csre0 + NE, 0, 8 * sizeof(int2), stream);     // slop
    k_count<<<EB, 256, 0, stream>>>(e_dst, cnt, ord);
    k_offsets<<<NB, 256, 0, stream>>>(cnt, x, meta, curs + 0, flag1, idmap);
    k_fill<<<EB, 256, 0, stream>>>(e_src, e_dst, ord, meta, csre, csre0, flag1);
    k_s1pass<<<NB + EB + (BATCH * NQ + 255) / 256, 256, 0, stream>>>(
        flag1, meta, csre, e_src, e_dst, curs + 1, rec1, flag2, rec0);   // S1 + mark S2 + rec0
    k_s1pass<<<NB + EB, 256, 0, stream>>>(
        flag2, meta, csre, e_src, e_dst, curs + 2, rec2, flag3, nullptr); // S2 + mark S3
    k_s1pass<<<NB, 256, 0, stream>>>(
        flag3, meta, csre, e_src, e_dst, curs + 3, rec3, nullptr, nullptr); // S3

    // --- layer 0 via token table: embW = emb@W0 (1021 rows, clamped id map) ---
    hgemm<1, false, false, false, false, true, false><<<dim3(8, 8), 256, 0, stream>>>(
        emb, nullptr, nullptr, bt_hi + OFF_GCN, bt_lo + OFF_GCN,
        nullptr, embW, nullptr, FEAT, FEAT, idmap, nullptr);
    k_agg0<<<NN / 16, 256, 0, stream>>>(embW, emb, h, meta, csre0, gb + 0 * FEAT);

    // --- fused GCN layers: aggregate-then-GEMM, ping-pong h <-> hw ---
    // L1 @S3: h -> hw
    k_lagg<true, false><<<NN / 16, 256, 0, stream>>>(
        h, hw, rec3, csre, curs + 3, 0,
        bt_hi + OFF_GCN + 1 * 16384, bt_lo + OFF_GCN + 1 * 16384, gb + 1 * FEAT,
        nullptr, nullptr, nullptr, nullptr, nullptr);
    // L2 @S2: hw -> h
    k_lagg<true, false><<<NN / 16, 256, 0, stream>>>(
        hw, h, rec2, csre, curs + 2, 0,
        bt_hi + OFF_GCN + 2 * 16384, bt_lo + OFF_GCN + 2 * 16384, gb + 2 * FEAT,
        nullptr, nullptr, nullptr, nullptr, nullptr);
    // L3 @S1: h -> hw
    k_lagg<true, false><<<NN / 16, 256, 0, stream>>>(
        h, hw, rec1, csre, curs + 1, 0,
        bt_hi + OFF_GCN + 3 * 16384, bt_lo + OFF_GCN + 3 * 16384, gb + 3 * FEAT,
        nullptr, nullptr, nullptr, nullptr, nullptr);
    // L4 @S0 (dense, no leaky) + fused P0: hw -> Abuf/Bbuf directly
    k_lagg<false, true><<<(BATCH * NQ) / 16, 256, 0, stream>>>(
        hw, nullptr, rec0, csre, nullptr, BATCH * NQ,
        bt_hi + OFF_GCN + 4 * 16384, bt_lo + OFF_GCN + 4 * 16384, gb + 4 * FEAT,
        bt_hi + OFF_P0, bt_lo + OFF_P0, mb0, Abuf, Bbuf);

    // --- fused pair MLP M1..M5 + atomic symmetrize -> out ---
    k_pair<<<NPAIR / 64, 256, 0, stream>>>(Abuf, Bbuf, bt_hi, bt_lo,
                                           mb1, mb2, mb3, mb4, mw5, mb5, out);
}